// Round 1
// baseline (193.132 us; speedup 1.0000x reference)
//
#include <hip/hip_runtime.h>
#include <hip/hip_bf16.h>

// KPConv: N=50000 queries, M=50000 support, H=32 neighbors, K=15 kernel pts,
// CIN=64, COUT=128, P=3. KP_EXTENT=0.072.
//
// Pipeline:
//   k1: transpose+convert weights [15,64,128] f32 -> Wt [128][960] bf16 (ws)
//   k2: per-point aggregate: wf[n][k*64+c] = sum_h w[h][k]*x[idx_h][c]  (bf16, ws)
//   k3: GEMM out[50000,128] = wf[50048,960] x Wt^T (bf16 MFMA, fp32 acc) + bias

#define NPTS   50000
#define NPAD   50048      // multiple of 128
#define HNB    32
#define KPTS   15
#define CING   64
#define COUTG  128
#define KDIM   960        // KPTS*CING
#define INV_EXT 13.888889f // 1/0.072

typedef __attribute__((ext_vector_type(8))) short bf16x8;
typedef __attribute__((ext_vector_type(4))) float f32x4;

static __device__ __forceinline__ unsigned short f2bf(float f) {
    unsigned int u = __float_as_uint(f);
    u += 0x7FFFu + ((u >> 16) & 1u);   // round-to-nearest-even
    return (unsigned short)(u >> 16);
}

// ---------------- k1: weights transpose/convert ----------------
// grid 960 blocks x 128 threads. Wt[o][kc] = bf16(W[kc][o]) with kc=k*64+c.
__global__ void kpconv_wt(const float* __restrict__ wgt, unsigned short* __restrict__ Wt) {
    int kc = blockIdx.x;
    int o  = threadIdx.x;
    Wt[(size_t)o * KDIM + kc] = f2bf(wgt[(size_t)kc * COUTG + o]);
}

// ---------------- k2: gather + aggregate ----------------
// grid 12500 blocks x 256 threads; 4 points/block, 64 threads (=CIN) per point.
__global__ __launch_bounds__(256) void kpconv_agg(
    const float* __restrict__ q_pts, const float* __restrict__ s_pts,
    const int* __restrict__ inds, const float* __restrict__ x,
    const float* __restrict__ kpts, unsigned short* __restrict__ wf)
{
    __shared__ float kp[48];            // 45 used
    __shared__ float nb[4][HNB][3];
    __shared__ int   sidx[4][HNB];
    __shared__ float w[4][HNB][16];     // k=15 padded to 16 for float4 reads

    const int tid = threadIdx.x;
    const int g   = tid >> 6;
    const int c   = tid & 63;
    const int n   = blockIdx.x * 4 + g;

    if (tid < 45) kp[tid] = kpts[tid];
    if (c < HNB) {
        int m = inds[n * HNB + c];
        sidx[g][c] = m;
        float qx = q_pts[n * 3 + 0];
        float qy = q_pts[n * 3 + 1];
        float qz = q_pts[n * 3 + 2];
        nb[g][c][0] = s_pts[(size_t)m * 3 + 0] - qx;
        nb[g][c][1] = s_pts[(size_t)m * 3 + 1] - qy;
        nb[g][c][2] = s_pts[(size_t)m * 3 + 2] - qz;
    }
    __syncthreads();

    // 32x16 = 512 slots per group, 64 threads -> 8 iters
    for (int i = c; i < 512; i += 64) {
        int h = i >> 4, k = i & 15;
        float v = 0.f;
        if (k < KPTS) {
            float dx = nb[g][h][0] - kp[k * 3 + 0];
            float dy = nb[g][h][1] - kp[k * 3 + 1];
            float dz = nb[g][h][2] - kp[k * 3 + 2];
            float d  = sqrtf(dx * dx + dy * dy + dz * dz);
            v = fmaxf(0.f, 1.f - d * INV_EXT);
        }
        w[g][h][k] = v;
    }
    __syncthreads();

    float acc[KPTS];
#pragma unroll
    for (int k = 0; k < KPTS; ++k) acc[k] = 0.f;

#pragma unroll 8
    for (int h = 0; h < HNB; ++h) {
        float xv = x[(size_t)sidx[g][h] * CING + c];
        float4 w0 = *(float4*)&w[g][h][0];
        float4 w1 = *(float4*)&w[g][h][4];
        float4 w2 = *(float4*)&w[g][h][8];
        float4 w3 = *(float4*)&w[g][h][12];
        acc[0]  = fmaf(w0.x, xv, acc[0]);
        acc[1]  = fmaf(w0.y, xv, acc[1]);
        acc[2]  = fmaf(w0.z, xv, acc[2]);
        acc[3]  = fmaf(w0.w, xv, acc[3]);
        acc[4]  = fmaf(w1.x, xv, acc[4]);
        acc[5]  = fmaf(w1.y, xv, acc[5]);
        acc[6]  = fmaf(w1.z, xv, acc[6]);
        acc[7]  = fmaf(w1.w, xv, acc[7]);
        acc[8]  = fmaf(w2.x, xv, acc[8]);
        acc[9]  = fmaf(w2.y, xv, acc[9]);
        acc[10] = fmaf(w2.z, xv, acc[10]);
        acc[11] = fmaf(w2.w, xv, acc[11]);
        acc[12] = fmaf(w3.x, xv, acc[12]);
        acc[13] = fmaf(w3.y, xv, acc[13]);
        acc[14] = fmaf(w3.z, xv, acc[14]);
    }

#pragma unroll
    for (int k = 0; k < KPTS; ++k)
        wf[(size_t)n * KDIM + k * CING + c] = f2bf(acc[k]);
}

// ---------------- k3: GEMM [NPAD,960] x [960,128] via bf16 MFMA ----------------
// 391 blocks x 256 threads (4 waves). Tile 128Mx128N, BK=32.
// Wave w: rows [32w,32w+32) x all 128 cols -> 2x8 mfma_16x16x32 per K-step.
#define BK    32
#define LDP   40   // LDS row pitch (elems): 32 + 8 pad -> 2-way bank alias (free)

__global__ __launch_bounds__(256) void kpconv_gemm(
    const unsigned short* __restrict__ A,   // wf [NPAD][960]
    const unsigned short* __restrict__ Bt,  // Wt [128][960]
    const float* __restrict__ bias,
    float* __restrict__ out)                // [50000][128]
{
    __shared__ unsigned short As[128 * LDP];
    __shared__ unsigned short Bs[128 * LDP];

    const int tid  = threadIdx.x;
    const int wave = tid >> 6;
    const int lane = tid & 63;
    const int l15  = lane & 15;
    const int quad = lane >> 4;
    const long blockM = (long)blockIdx.x * 128;

    f32x4 acc[2][8];
#pragma unroll
    for (int i = 0; i < 2; ++i)
#pragma unroll
        for (int j = 0; j < 8; ++j) acc[i][j] = (f32x4){0.f, 0.f, 0.f, 0.f};

    const int srow = tid >> 1;          // 0..127
    const int scol = (tid & 1) * 16;    // 0 or 16
    const size_t aBase = (size_t)(blockM + srow) * KDIM + scol;
    const size_t bBase = (size_t)srow * KDIM + scol;

    for (int kk = 0; kk < KDIM; kk += BK) {
        uint4 a0 = *(const uint4*)(A + aBase + kk);
        uint4 a1 = *(const uint4*)(A + aBase + kk + 8);
        uint4 b0 = *(const uint4*)(Bt + bBase + kk);
        uint4 b1 = *(const uint4*)(Bt + bBase + kk + 8);
        __syncthreads();   // previous iter's frag reads complete
        *(uint4*)&As[srow * LDP + scol]     = a0;
        *(uint4*)&As[srow * LDP + scol + 8] = a1;
        *(uint4*)&Bs[srow * LDP + scol]     = b0;
        *(uint4*)&Bs[srow * LDP + scol + 8] = b1;
        __syncthreads();

        bf16x8 af[2], bfr[8];
#pragma unroll
        for (int mf = 0; mf < 2; ++mf)
            af[mf] = *(bf16x8*)&As[(wave * 32 + mf * 16 + l15) * LDP + quad * 8];
#pragma unroll
        for (int nf = 0; nf < 8; ++nf)
            bfr[nf] = *(bf16x8*)&Bs[(nf * 16 + l15) * LDP + quad * 8];
#pragma unroll
        for (int mf = 0; mf < 2; ++mf)
#pragma unroll
            for (int nf = 0; nf < 8; ++nf)
                acc[mf][nf] = __builtin_amdgcn_mfma_f32_16x16x32_bf16(
                    af[mf], bfr[nf], acc[mf][nf], 0, 0, 0);
    }

    // epilogue: D[row][col], col = l15 (+16*nf), row = quad*4 + reg (+16*mf + 32*wave)
#pragma unroll
    for (int mf = 0; mf < 2; ++mf) {
        long r0 = blockM + wave * 32 + mf * 16 + quad * 4;
#pragma unroll
        for (int nf = 0; nf < 8; ++nf) {
            int col = nf * 16 + l15;
            float bv = bias[col];
#pragma unroll
            for (int r = 0; r < 4; ++r) {
                long row = r0 + r;
                if (row < NPTS) out[row * COUTG + col] = acc[mf][nf][r] + bv;
            }
        }
    }
}

extern "C" void kernel_launch(void* const* d_in, const int* in_sizes, int n_in,
                              void* d_out, int out_size, void* d_ws, size_t ws_size,
                              hipStream_t stream) {
    const float* q_pts = (const float*)d_in[0];
    const float* s_pts = (const float*)d_in[1];
    const int*   inds  = (const int*)d_in[2];
    const float* x     = (const float*)d_in[3];
    const float* kpts  = (const float*)d_in[4];
    const float* wgt   = (const float*)d_in[5];
    const float* bias  = (const float*)d_in[6];
    float* out = (float*)d_out;

    // workspace layout: wf [NPAD*960] bf16, then Wt [128*960] bf16
    unsigned short* wf = (unsigned short*)d_ws;
    unsigned short* Wt = wf + (size_t)NPAD * KDIM;

    kpconv_wt<<<KDIM, COUTG, 0, stream>>>(wgt, Wt);
    kpconv_agg<<<NPTS / 4, 256, 0, stream>>>(q_pts, s_pts, inds, x, kpts, wf);
    kpconv_gemm<<<NPAD / 128, 256, 0, stream>>>(wf, Wt, bias, out);
}

// Round 2
// 159.518 us; speedup vs baseline: 1.2107x; 1.2107x over previous
//
#include <hip/hip_runtime.h>
#include <hip/hip_bf16.h>

// KPConv pipeline v2:
//   k0: x [50000,64] f32 -> xb bf16 (halves gather traffic)
//   k1: weights [15,64,128] f32 -> Wt [128][960] bf16 (transposed)
//   k2: MFMA aggregate: per point, wf[k,c] = sum_h w(h,k)*x(h,c) as one
//       16x16x32 bf16 MFMA (A = w in-register, B = gathered x u16 loads)
//   k3: GEMM out[50000,128] = wf[50048,960] x Wt^T, 64x128 tiles, BK=64,
//       register-prefetch pipeline, 782 blocks.

#define NPTS   50000
#define NPAD   50048
#define HNB    32
#define KPTS   15
#define CING   64
#define COUTG  128
#define KDIM   960
#define MSUP   50000          // support points
#define INV_EXT 13.888889f

typedef __attribute__((ext_vector_type(8))) short bf16x8;
typedef __attribute__((ext_vector_type(8))) unsigned short u16x8;
typedef __attribute__((ext_vector_type(4))) float f32x4;

static __device__ __forceinline__ unsigned short f2bf(float f) {
    unsigned int u = __float_as_uint(f);
    u += 0x7FFFu + ((u >> 16) & 1u);
    return (unsigned short)(u >> 16);
}

// ---------------- k0: x -> bf16 ----------------
__global__ __launch_bounds__(256) void kpconv_x2bf(const float* __restrict__ x,
                                                   unsigned short* __restrict__ xb) {
    int i = (blockIdx.x * 256 + threadIdx.x) * 8;
    if (i >= MSUP * CING) return;
    float4 a = *(const float4*)(x + i);
    float4 b = *(const float4*)(x + i + 4);
    u16x8 o;
    o[0] = f2bf(a.x); o[1] = f2bf(a.y); o[2] = f2bf(a.z); o[3] = f2bf(a.w);
    o[4] = f2bf(b.x); o[5] = f2bf(b.y); o[6] = f2bf(b.z); o[7] = f2bf(b.w);
    *(u16x8*)(xb + i) = o;
}

// ---------------- k1: weights transpose ----------------
__global__ void kpconv_wt(const float* __restrict__ wgt, unsigned short* __restrict__ Wt) {
    int kc = blockIdx.x;
    int o  = threadIdx.x;
    Wt[(size_t)o * KDIM + kc] = f2bf(wgt[(size_t)kc * COUTG + o]);
}

// ---------------- k2: MFMA aggregate ----------------
// 1 wave = 1 point. Block 256 threads = 4 points. Grid 12500.
// A-frag (w): lane k=l15, h=quad*8+j, computed in-register.
// B-frag (x): lane c=l15+16*nt, h=quad*8+j, gathered u16 from xb.
// D: row k=quad*4+reg, col c=l15 (+16*nt).
__global__ __launch_bounds__(256) void kpconv_agg2(
    const float* __restrict__ q_pts, const float* __restrict__ s_pts,
    const int* __restrict__ inds, const unsigned short* __restrict__ xb,
    const float* __restrict__ kpts, unsigned short* __restrict__ wf)
{
    __shared__ float4 nb4[4][HNB];

    const int tid  = threadIdx.x;
    const int g    = tid >> 6;
    const int lane = tid & 63;
    const int l15  = lane & 15;
    const int quad = lane >> 4;
    const int n    = blockIdx.x * 4 + g;

    if (lane < HNB) {
        int m = inds[n * HNB + lane];
        float qx = q_pts[n * 3 + 0];
        float qy = q_pts[n * 3 + 1];
        float qz = q_pts[n * 3 + 2];
        nb4[g][lane] = make_float4(s_pts[m * 3 + 0] - qx,
                                   s_pts[m * 3 + 1] - qy,
                                   s_pts[m * 3 + 2] - qz,
                                   __int_as_float(m));
    }
    __syncthreads();

    const bool kvalid = (l15 < KPTS);
    const int  kidx   = kvalid ? l15 : 0;
    const float kx = kpts[kidx * 3 + 0];
    const float ky = kpts[kidx * 3 + 1];
    const float kz = kpts[kidx * 3 + 2];

    bf16x8 af;
    int mrow[8];
#pragma unroll
    for (int j = 0; j < 8; ++j) {
        float4 v = nb4[g][quad * 8 + j];
        mrow[j] = __float_as_int(v.w);
        float dx = v.x - kx, dy = v.y - ky, dz = v.z - kz;
        float d  = sqrtf(dx * dx + dy * dy + dz * dz);
        float w  = kvalid ? fmaxf(0.f, 1.f - d * INV_EXT) : 0.f;
        af[j] = (short)f2bf(w);
    }

    f32x4 acc[4];
#pragma unroll
    for (int nt = 0; nt < 4; ++nt) acc[nt] = (f32x4){0.f, 0.f, 0.f, 0.f};

#pragma unroll
    for (int nt = 0; nt < 4; ++nt) {
        const int c = nt * 16 + l15;
        bf16x8 bfr;
#pragma unroll
        for (int j = 0; j < 8; ++j)
            bfr[j] = (short)xb[((size_t)mrow[j] << 6) + c];
        acc[nt] = __builtin_amdgcn_mfma_f32_16x16x32_bf16(af, bfr, acc[nt], 0, 0, 0);
    }

    const size_t base = (size_t)n * KDIM;
#pragma unroll
    for (int nt = 0; nt < 4; ++nt) {
        const int c = nt * 16 + l15;
#pragma unroll
        for (int r = 0; r < 4; ++r) {
            int k = quad * 4 + r;
            if (k < KPTS) wf[base + k * CING + c] = f2bf(acc[nt][r]);
        }
    }
}

// ---------------- k3: GEMM 64x128, BK=64, reg prefetch ----------------
#define GBM 64
#define GBK 64
#define GLP 72   // LDS pitch elems (144 B: 16B-aligned rows, bank-step 36=4*odd)

__global__ __launch_bounds__(256) void kpconv_gemm2(
    const unsigned short* __restrict__ A,   // wf [NPAD][960]
    const unsigned short* __restrict__ Bt,  // Wt [128][960]
    const float* __restrict__ bias,
    float* __restrict__ out)
{
    __shared__ unsigned short As[GBM * GLP];    // 9216 B
    __shared__ unsigned short Bs[COUTG * GLP];  // 18432 B

    const int tid  = threadIdx.x;
    const int wave = tid >> 6;
    const int lane = tid & 63;
    const int l15  = lane & 15;
    const int quad = lane >> 4;
    const long blockM = (long)blockIdx.x * GBM;

    f32x4 acc[8];
#pragma unroll
    for (int i = 0; i < 8; ++i) acc[i] = (f32x4){0.f, 0.f, 0.f, 0.f};

    // staging: A 64 rows x 64 cols (4 thr/row, 16 elems each -> 2 uint4)
    //          B 128 rows x 64 cols (2 thr/row, 32 elems each -> 4 uint4)
    const int arow = tid >> 2, acol = (tid & 3) * 16;
    const int brow = tid >> 1, bcol = (tid & 1) * 32;
    const unsigned short* aptr = A + (size_t)(blockM + arow) * KDIM + acol;
    const unsigned short* bptr = Bt + (size_t)brow * KDIM + bcol;

    uint4 ra0 = *(const uint4*)(aptr);
    uint4 ra1 = *(const uint4*)(aptr + 8);
    uint4 rb0 = *(const uint4*)(bptr);
    uint4 rb1 = *(const uint4*)(bptr + 8);
    uint4 rb2 = *(const uint4*)(bptr + 16);
    uint4 rb3 = *(const uint4*)(bptr + 24);

    for (int kk = 0; kk < KDIM; kk += GBK) {
        __syncthreads();   // previous iter's frag reads complete
        *(uint4*)&As[arow * GLP + acol]      = ra0;
        *(uint4*)&As[arow * GLP + acol + 8]  = ra1;
        *(uint4*)&Bs[brow * GLP + bcol]      = rb0;
        *(uint4*)&Bs[brow * GLP + bcol + 8]  = rb1;
        *(uint4*)&Bs[brow * GLP + bcol + 16] = rb2;
        *(uint4*)&Bs[brow * GLP + bcol + 24] = rb3;
        __syncthreads();

        if (kk + GBK < KDIM) {   // prefetch next tile into regs (overlaps MFMA)
            ra0 = *(const uint4*)(aptr + kk + GBK);
            ra1 = *(const uint4*)(aptr + kk + GBK + 8);
            rb0 = *(const uint4*)(bptr + kk + GBK);
            rb1 = *(const uint4*)(bptr + kk + GBK + 8);
            rb2 = *(const uint4*)(bptr + kk + GBK + 16);
            rb3 = *(const uint4*)(bptr + kk + GBK + 24);
        }

#pragma unroll
        for (int ch = 0; ch < 2; ++ch) {
            bf16x8 afr = *(bf16x8*)&As[(wave * 16 + l15) * GLP + ch * 32 + quad * 8];
#pragma unroll
            for (int nf = 0; nf < 8; ++nf) {
                bf16x8 bfr = *(bf16x8*)&Bs[(nf * 16 + l15) * GLP + ch * 32 + quad * 8];
                acc[nf] = __builtin_amdgcn_mfma_f32_16x16x32_bf16(afr, bfr, acc[nf], 0, 0, 0);
            }
        }
    }

    const long r0 = blockM + wave * 16 + quad * 4;
#pragma unroll
    for (int nf = 0; nf < 8; ++nf) {
        const int col = nf * 16 + l15;
        const float bv = bias[col];
#pragma unroll
        for (int r = 0; r < 4; ++r) {
            long row = r0 + r;
            if (row < NPTS) out[row * COUTG + col] = acc[nf][r] + bv;
        }
    }
}

extern "C" void kernel_launch(void* const* d_in, const int* in_sizes, int n_in,
                              void* d_out, int out_size, void* d_ws, size_t ws_size,
                              hipStream_t stream) {
    const float* q_pts = (const float*)d_in[0];
    const float* s_pts = (const float*)d_in[1];
    const int*   inds  = (const int*)d_in[2];
    const float* x     = (const float*)d_in[3];
    const float* kpts  = (const float*)d_in[4];
    const float* wgt   = (const float*)d_in[5];
    const float* bias  = (const float*)d_in[6];
    float* out = (float*)d_out;

    // ws layout: wf [NPAD*960] bf16 | xb [50000*64] bf16 | Wt [128*960] bf16
    unsigned short* wf = (unsigned short*)d_ws;
    unsigned short* xb = wf + (size_t)NPAD * KDIM;
    unsigned short* Wt = xb + (size_t)MSUP * CING;

    kpconv_x2bf<<<(MSUP * CING / 8 + 255) / 256, 256, 0, stream>>>(x, xb);
    kpconv_wt<<<KDIM, COUTG, 0, stream>>>(wgt, Wt);
    kpconv_agg2<<<NPTS / 4, 256, 0, stream>>>(q_pts, s_pts, inds, xb, kpts, wf);
    kpconv_gemm2<<<NPAD / GBM, 256, 0, stream>>>(wf, Wt, bias, out);
}